// Round 1
// baseline (7900.626 us; speedup 1.0000x reference)
//
#include <hip/hip_runtime.h>
#include <stdint.h>

#define T_ 1024

typedef float  floatx4 __attribute__((ext_vector_type(4)));
typedef short  shortx8 __attribute__((ext_vector_type(8)));

__device__ __forceinline__ unsigned short f2bf(float f) {
  union { float f; unsigned u; } v; v.f = f;
  return (unsigned short)((v.u + 0x7FFFu + ((v.u >> 16) & 1u)) >> 16);
}
__device__ __forceinline__ float bf2f(unsigned short h) {
  union { unsigned u; float f; } v; v.u = ((unsigned)h) << 16; return v.f;
}

// ---- prep: pack rows [W_hh | W_ih] to bf16 (wcat0: 3072x1280, wcat1: 3072x2048), zero flags ----
__global__ void prep_kernel(const float* __restrict__ wih0, const float* __restrict__ whh0,
                            const float* __restrict__ wih1, const float* __restrict__ whh1,
                            unsigned short* __restrict__ wcat0, unsigned short* __restrict__ wcat1,
                            unsigned* __restrict__ f0, unsigned* __restrict__ f1) {
  long gid = (long)blockIdx.x * 256 + threadIdx.x;
  if (gid < 1024) f0[gid] = 0u;
  else if (gid < 2048) f1[gid - 1024] = 0u;
  const long n0 = 3072L * 1280 / 8;
  const long n1 = 3072L * 2048 / 8;
  union { unsigned short s[8]; uint4 v; } t;
  if (gid < n0) {
    long e = gid * 8; int row = (int)(e / 1280); int k = (int)(e % 1280);
    const float* src = (k < 1024) ? (whh0 + (long)row * 1024 + k)
                                  : (wih0 + (long)row * 256 + (k - 1024));
#pragma unroll
    for (int j = 0; j < 8; ++j) t.s[j] = f2bf(src[j]);
    *(uint4*)(wcat0 + e) = t.v;
  } else if (gid < n0 + n1) {
    long e = (gid - n0) * 8; int row = (int)(e / 2048); int k = (int)(e % 2048);
    const float* src = (k < 1024) ? (whh1 + (long)row * 1024 + k)
                                  : (wih1 + (long)row * 1024 + (k - 1024));
#pragma unroll
    for (int j = 0; j < 8; ++j) t.s[j] = f2bf(src[j]);
    *(uint4*)(wcat1 + e) = t.v;
  }
}

// ---- persistent GRU: 64 blocks/layer, 16 hidden cols/block, weights in VGPRs ----
template<int L>
__device__ __forceinline__ void gru_body(int lb, int tid,
    const float* __restrict__ x,
    const unsigned short* __restrict__ wcat,
    const float* __restrict__ bihg, const float* __restrict__ bhhg,
    unsigned short* __restrict__ y0buf, float* __restrict__ dout,
    unsigned* fprod, unsigned* fdep,
    unsigned short* inp, float (*part)[4][272], float* bih_s, float* bhh_s)
{
  constexpr int KW  = L ? 2048 : 1280;   // [h (1024) | x (256 or 1024)]
  constexpr int IS  = KW + 16;           // padded LDS row stride (bf16 elems)
  constexpr int KTX = L ? 4 : 1;         // x-part k-tiles per wave
  constexpr int XW  = L ? 128 : 32;      // per-wave x-chunk width
  const int cb = lb * 16;
  const int w  = tid >> 6;
  const int l  = tid & 63;
  const int lr = l & 15, lq = l >> 4;

  if (tid < 48) {
    int g = tid >> 4, c = tid & 15;
    bih_s[tid] = bihg[g * 1024 + cb + c];
    bhh_s[tid] = bhhg[g * 1024 + cb + c];
  }

  // B-fragments resident in registers for the whole time loop.
  // A and B use the SAME (lq, e) -> k mapping, so intra-tile k-permutation cancels.
  shortx8 bfh[3][4];
  shortx8 bfx[3][KTX];
#pragma unroll
  for (int g = 0; g < 3; ++g) {
    const unsigned short* wr = wcat + (long)(g * 1024 + cb + lr) * KW;
#pragma unroll
    for (int kt = 0; kt < 4; ++kt)
      bfh[g][kt] = *(const shortx8*)(wr + w * 128 + kt * 32 + lq * 8);
#pragma unroll
    for (int kt = 0; kt < KTX; ++kt)
      bfx[g][kt] = *(const shortx8*)(wr + 1024 + w * XW + kt * 32 + lq * 8);
  }
  __syncthreads();

  const int sb = tid >> 5, sg = tid & 31;  // staging map: batch, 32-elem segment

  for (int t = 0; t < T_; ++t) {
    if (tid == 0) {
      if (L == 1) {
        while (__hip_atomic_load(fdep + t, __ATOMIC_ACQUIRE, __HIP_MEMORY_SCOPE_AGENT) < 64u)
          __builtin_amdgcn_s_sleep(1);
      }
      if (t > 0) {
        while (__hip_atomic_load(fprod + (t - 1), __ATOMIC_ACQUIRE, __HIP_MEMORY_SCOPE_AGENT) < 64u)
          __builtin_amdgcn_s_sleep(1);
      }
    }
    __syncthreads();

    // ---- stage h_prev (+ x or y0) into LDS as bf16 ----
    {
      unsigned short* dh = inp + sb * IS + sg * 32;
      if (t > 0) {
        if (L == 0) {
          const uint4* s = (const uint4*)(y0buf + ((long)(t - 1) * 16 + sb) * 1024 + sg * 32);
          uint4* d4 = (uint4*)dh;
          d4[0] = s[0]; d4[1] = s[1]; d4[2] = s[2]; d4[3] = s[3];
        } else {
          const float4* s4 = (const float4*)(dout + (long)sb * (T_ * 1024) + (long)(t - 1) * 1024 + sg * 32);
          unsigned* du = (unsigned*)dh;
#pragma unroll
          for (int j = 0; j < 8; ++j) {
            float4 v = s4[j];
            du[2 * j]     = (unsigned)f2bf(v.x) | ((unsigned)f2bf(v.y) << 16);
            du[2 * j + 1] = (unsigned)f2bf(v.z) | ((unsigned)f2bf(v.w) << 16);
          }
        }
      } else {
        uint4 zz; zz.x = zz.y = zz.z = zz.w = 0u;
        uint4* d4 = (uint4*)dh;
        d4[0] = zz; d4[1] = zz; d4[2] = zz; d4[3] = zz;
      }
      if (L == 0) {
        if (tid < 256) {
          int b2 = tid >> 4, s2 = tid & 15;
          const float4* s4 = (const float4*)(x + (long)b2 * (T_ * 256) + (long)t * 256 + s2 * 16);
          unsigned* du = (unsigned*)(inp + b2 * IS + 1024 + s2 * 16);
#pragma unroll
          for (int j = 0; j < 4; ++j) {
            float4 v = s4[j];
            du[2 * j]     = (unsigned)f2bf(v.x) | ((unsigned)f2bf(v.y) << 16);
            du[2 * j + 1] = (unsigned)f2bf(v.z) | ((unsigned)f2bf(v.w) << 16);
          }
        }
      } else {
        const uint4* s = (const uint4*)(y0buf + ((long)t * 16 + sb) * 1024 + sg * 32);
        uint4* d4 = (uint4*)(inp + sb * IS + 1024 + sg * 32);
        d4[0] = s[0]; d4[1] = s[1]; d4[2] = s[2]; d4[3] = s[3];
      }
    }
    __syncthreads();

    // ---- MFMA: D[b][col] over K = [h | x]; n-gate split into h-part / x-part ----
    floatx4 ar = {0.f, 0.f, 0.f, 0.f};
    floatx4 az = ar, anh = ar, anx = ar;
    const unsigned short* arow = inp + lr * IS;
#pragma unroll
    for (int kt = 0; kt < 4; ++kt) {
      shortx8 A = *(const shortx8*)(arow + w * 128 + kt * 32 + lq * 8);
      ar  = __builtin_amdgcn_mfma_f32_16x16x32_bf16(A, bfh[0][kt], ar,  0, 0, 0);
      az  = __builtin_amdgcn_mfma_f32_16x16x32_bf16(A, bfh[1][kt], az,  0, 0, 0);
      anh = __builtin_amdgcn_mfma_f32_16x16x32_bf16(A, bfh[2][kt], anh, 0, 0, 0);
    }
#pragma unroll
    for (int kt = 0; kt < KTX; ++kt) {
      shortx8 A = *(const shortx8*)(arow + 1024 + w * XW + kt * 32 + lq * 8);
      ar  = __builtin_amdgcn_mfma_f32_16x16x32_bf16(A, bfx[0][kt], ar,  0, 0, 0);
      az  = __builtin_amdgcn_mfma_f32_16x16x32_bf16(A, bfx[1][kt], az,  0, 0, 0);
      anx = __builtin_amdgcn_mfma_f32_16x16x32_bf16(A, bfx[2][kt], anx, 0, 0, 0);
    }
    // C/D layout (m89-verified): col = lane&15, row = (lane>>4)*4 + reg  (row = batch)
#pragma unroll
    for (int r4 = 0; r4 < 4; ++r4) {
      int idx = (lq * 4 + r4) * 17 + lr;
      part[w][0][idx] = ar[r4];
      part[w][1][idx] = az[r4];
      part[w][2][idx] = anh[r4];
      part[w][3][idx] = anx[r4];
    }
    __syncthreads();

    // ---- gates + state update (one thread per (batch, col)) ----
    if (tid < 256) {
      int b = tid >> 4, c = tid & 15, idx = b * 17 + c;
      float sr = 0.f, sz = 0.f, snh = 0.f, snx = 0.f;
#pragma unroll
      for (int ww = 0; ww < 8; ++ww) {
        sr  += part[ww][0][idx];
        sz  += part[ww][1][idx];
        snh += part[ww][2][idx];
        snx += part[ww][3][idx];
      }
      float r = 1.f / (1.f + expf(-(sr + bih_s[c]      + bhh_s[c])));
      float z = 1.f / (1.f + expf(-(sz + bih_s[16 + c] + bhh_s[16 + c])));
      float n = tanhf(snx + bih_s[32 + c] + r * (snh + bhh_s[32 + c]));
      float hp = (t > 0) ? bf2f(inp[b * IS + cb + c]) : 0.f;
      float hn = (1.f - z) * n + z * hp;
      if (L == 0) {
        y0buf[((long)t * 16 + b) * 1024 + cb + c] = f2bf(hn);
        if (t == T_ - 1) dout[16777216L + (long)b * 1024 + cb + c] = hn;
      } else {
        dout[(long)b * (T_ * 1024) + (long)t * 1024 + cb + c] = hn;
        if (t == T_ - 1) dout[16777216L + 16384 + (long)b * 1024 + cb + c] = hn;
      }
    }
    __syncthreads();  // drains vmcnt for all threads' global stores
    if (tid == 0)
      __hip_atomic_fetch_add(fprod + t, 1u, __ATOMIC_RELEASE, __HIP_MEMORY_SCOPE_AGENT);
  }
}

__global__ __launch_bounds__(512) void gru_kernel(
    const float* __restrict__ x,
    const unsigned short* __restrict__ wcat0, const unsigned short* __restrict__ wcat1,
    const float* __restrict__ bih0, const float* __restrict__ bhh0,
    const float* __restrict__ bih1, const float* __restrict__ bhh1,
    unsigned short* y0buf, float* dout, unsigned* f0, unsigned* f1)
{
  __shared__ __align__(16) unsigned short inp[16 * 2064];  // 66048 B (L0 uses stride 1296)
  __shared__ float part[8][4][272];                        // 34816 B
  __shared__ float bih_s[48];
  __shared__ float bhh_s[48];
  const int bid = blockIdx.x, tid = threadIdx.x;
  if (bid < 64)
    gru_body<0>(bid, tid, x, wcat0, bih0, bhh0, y0buf, dout, f0, f1, inp, part, bih_s, bhh_s);
  else
    gru_body<1>(bid - 64, tid, x, wcat1, bih1, bhh1, y0buf, dout, f1, f0, inp, part, bih_s, bhh_s);
}

extern "C" void kernel_launch(void* const* d_in, const int* in_sizes, int n_in,
                              void* d_out, int out_size, void* d_ws, size_t ws_size,
                              hipStream_t stream) {
  (void)in_sizes; (void)n_in; (void)out_size; (void)ws_size;
  const float* x    = (const float*)d_in[0];
  const float* wih0 = (const float*)d_in[2];
  const float* whh0 = (const float*)d_in[3];
  const float* bih0 = (const float*)d_in[4];
  const float* bhh0 = (const float*)d_in[5];
  const float* wih1 = (const float*)d_in[6];
  const float* whh1 = (const float*)d_in[7];
  const float* bih1 = (const float*)d_in[8];
  const float* bhh1 = (const float*)d_in[9];
  char* ws = (char*)d_ws;
  unsigned short* wcat0 = (unsigned short*)(ws + 0L);
  unsigned short* wcat1 = (unsigned short*)(ws + 7864320L);
  unsigned short* y0buf = (unsigned short*)(ws + 20447232L);
  unsigned* f0 = (unsigned*)(ws + 54001664L);
  unsigned* f1 = (unsigned*)(ws + 54005760L);
  float* out = (float*)d_out;

  prep_kernel<<<4992, 256, 0, stream>>>(wih0, whh0, wih1, whh1, wcat0, wcat1, f0, f1);
  gru_kernel<<<128, 512, 0, stream>>>(x, wcat0, wcat1, bih0, bhh0, bih1, bhh1, y0buf, out, f0, f1);
}